// Round 3
// baseline (759.093 us; speedup 1.0000x reference)
//
#include <hip/hip_runtime.h>
#include <cstdint>

#define NB 16      // clouds
#define NP 4096    // points per cloud
#define MC 1024    // FPS centers per cloud
#define KNN 64     // neighbors
#define CIN 64     // input feature dim
#define HID 64
#define OUTD 128

typedef __attribute__((ext_vector_type(8))) short bf16x8;
typedef __attribute__((ext_vector_type(4))) float f32x4;
typedef __attribute__((ext_vector_type(2))) float f32x2;
typedef unsigned long long ull;
typedef unsigned short ushort_t;

#define F32_INF __int_as_float(0x7f800000)
#define WSENT 0xFFFFFFFFu

// LDS-only barrier: orders DS ops across the block WITHOUT draining vmcnt.
// __syncthreads() emits s_waitcnt vmcnt(0) before s_barrier, which would make the
// FPS block wait on t0's fire-and-forget widx publish store every iteration (~50us
// total). The loop only needs LDS ordering (kbuf/whist), so lgkmcnt(0) suffices.
#define BAR_LGKM() asm volatile("s_waitcnt lgkmcnt(0)\n\ts_barrier" ::: "memory")

// Bit-exact (vs numpy f32) squared distance: no FMA contraction, numpy sum order.
__device__ __forceinline__ float dist2e(float ax, float ay, float az,
                                        float bx, float by, float bz) {
  float dx = __fsub_rn(ax, bx);
  float dy = __fsub_rn(ay, by);
  float dz = __fsub_rn(az, bz);
  return __fadd_rn(__fadd_rn(__fmul_rn(dx, dx), __fmul_rn(dy, dy)), __fmul_rn(dz, dz));
}

// f32 -> bf16 with round-to-nearest-even.
__device__ __forceinline__ ushort_t f2bf(float f) {
  unsigned u = __float_as_uint(f);
  unsigned r = (u + 0x7FFFu + ((u >> 16) & 1u)) >> 16;
  return (ushort_t)r;
}

// ---- DPP helpers: 64-bit key max-reduce on the VALU pipe ----
template <int CTRL>
__device__ __forceinline__ ull kshift(ull k) {
  int lo = (int)(unsigned)(k & 0xffffffffULL);
  int hi = (int)(unsigned)(k >> 32);
  lo = __builtin_amdgcn_update_dpp(lo, lo, CTRL, 0xf, 0xf, false);
  hi = __builtin_amdgcn_update_dpp(hi, hi, CTRL, 0xf, 0xf, false);
  return ((ull)(unsigned)hi << 32) | (ull)(unsigned)lo;
}
template <int CTRL>
__device__ __forceinline__ ull kred(ull k) {
  ull o = kshift<CTRL>(k);
  return (o > k) ? o : k;
}

// ---------- W -> MFMA B-fragment layout (writes LDS or global) ----------
__device__ __forceinline__ void wfrag_entry(const float* __restrict__ W,
                                            ushort_t* __restrict__ out,
                                            int e, int KS, int K, int N) {
  int lane = e & 63, t2 = e >> 6;
  int ks = t2 % KS, nt = t2 / KS;
  int n = nt * 16 + (lane & 15);
  int kb = ks * 32 + ((lane >> 4) & 3) * 8;
#pragma unroll
  for (int j = 0; j < 8; ++j) {
    int k = kb + j;
    float v = (k < K) ? W[(size_t)k * N + n] : 0.f;
    out[(size_t)e * 8 + j] = f2bf(v);
  }
}

// Re-poison the per-center published-index array each launch (ws persists).
__global__ void init_widx(unsigned* __restrict__ widx) {
  int i = blockIdx.x * 256 + threadIdx.x;
  if (i < NB * MC) widx[i] = WSENT;
}

// ================= Mega-kernel: FPS producers (blocks 0..15) + streaming workers =================
// FPS core = round-0 proven structure (4 waves, u64-key DPP reduce, one barrier/iter).
// r1 showed the dist phase is ISSUE-bound per SIMD (more waves don't shorten it); 4 waves
// is the sweet spot. r2 showed the per-iteration widx publish + __syncthreads' vmcnt(0)
// drain cost ~53us -> loop barrier is now lgkmcnt-only (BAR_LGKM), store stays in flight.
// Workers (blocks 16..255, 960 waves) consume centers in arrival order r=s*16+b: poll
// widx[c] (the ONLY cross-XCD datum; everything else recomputed from immutable inputs),
// then run neigh selection + MFMA MLP wave-locally. Grid=256 blocks <= 256 CUs with LDS
// 74.7KB => all blocks resident regardless of dispatch order => spin is deadlock-free.
__global__ __launch_bounds__(256) void mega_kernel(
    const float* __restrict__ point, const float* __restrict__ xyz,
    const float* __restrict__ W1, const float* __restrict__ W2, const float* __restrict__ W3,
    const float* __restrict__ b1, const float* __restrict__ b2, const float* __restrict__ b3,
    unsigned* __restrict__ widx,
    float* __restrict__ out, float* __restrict__ cent_out, float* __restrict__ batch_out) {
#pragma clang fp contract(off)
  __shared__ char __attribute__((aligned(16))) smem[74752];
  const int blk = blockIdx.x;
  const int t = threadIdx.x;

  if (blk < NB) {
    // ======================= FPS path (round-0 core) =======================
    const int b = blk;
    const int lane = t & 63, wid = t >> 6;
    float4* pts = (float4*)smem;                 // 65536 B
    ull* kbuf = (ull*)(smem + 65536);            // 2*4 slots = 64 B
    int* whist = (int*)(smem + 65600);           // 4096 B
    const float* p = point + (size_t)b * NP * 3;
    for (int i = t; i < NP; i += 256) {
      float4 v; v.x = p[3 * i]; v.y = p[3 * i + 1]; v.z = p[3 * i + 2]; v.w = 0.f;
      pts[i] = v;
    }
    if (t == 0) {
      whist[0] = 0;  // sample 0 is index 0
      __hip_atomic_store(widx + (size_t)b * MC, 0u, __ATOMIC_RELAXED, __HIP_MEMORY_SCOPE_AGENT);
    }
    __syncthreads();
    f32x2 qx2[8], qy2[8], qz2[8], d2v[8];
#pragma unroll
    for (int k = 0; k < 8; ++k) {
      float4 v0 = pts[t * 16 + 2 * k];
      float4 v1 = pts[t * 16 + 2 * k + 1];
      qx2[k].x = v0.x; qx2[k].y = v1.x;
      qy2[k].x = v0.y; qy2[k].y = v1.y;
      qz2[k].x = v0.z; qz2[k].y = v1.z;
      d2v[k].x = F32_INF; d2v[k].y = F32_INF;   // min(inf, d0) == d0 exactly
    }
    int w = 0;
    for (int it = 1; it < MC; ++it) {
      float4 wp = pts[w];
      f32x2 wxx; wxx.x = wp.x; wxx.y = wp.x;
      f32x2 wyy; wyy.x = wp.y; wyy.y = wp.y;
      f32x2 wzz; wzz.x = wp.z; wzz.y = wp.z;
      float bd = -1.0f; int br = 0;
#pragma unroll
      for (int k = 0; k < 8; ++k) {   // packed dist + min-update + first-max argmax
        f32x2 dx = qx2[k] - wxx;
        f32x2 dy = qy2[k] - wyy;
        f32x2 dz = qz2[k] - wzz;
        f32x2 nd = (dx * dx + dy * dy) + dz * dz;  // per-element numpy order, no fma
        f32x2 dv;
        dv.x = fminf(d2v[k].x, nd.x);
        dv.y = fminf(d2v[k].y, nd.y);
        d2v[k] = dv;
        bool p1 = dv.y > dv.x;                     // strict: tie keeps lower r
        float pd = p1 ? dv.y : dv.x;
        int pr = 2 * k + (p1 ? 1 : 0);
        if (pd > bd) { bd = pd; br = pr; }         // strict: first-occurrence wins
      }
      unsigned gi = (unsigned)(t * 16 + br);
      ull key = ((ull)__float_as_uint(bd) << 32) | (ull)(unsigned)~gi;
      key = kred<0x111>(key);  // row_shr:1
      key = kred<0x112>(key);  // row_shr:2
      key = kred<0x114>(key);  // row_shr:4
      key = kred<0x118>(key);  // row_shr:8   -> lane 15/31/47/63 = row max
      key = kred<0x142>(key);  // row_bcast:15
      key = kred<0x143>(key);  // row_bcast:31 -> lane 63 = wave max
      const int par = it & 1;                // parity: slot reused only after 2 barriers
      if (lane == 63) kbuf[par * 4 + wid] = key;
      BAR_LGKM();                            // LDS-only barrier: vmcnt publish stays in flight
      ull k0 = kbuf[par * 4 + 0], k1 = kbuf[par * 4 + 1];
      ull k2 = kbuf[par * 4 + 2], k3 = kbuf[par * 4 + 3];
      ull ka = (k0 > k1) ? k0 : k1;          // uniform LDS broadcast reads; every lane
      ull kb = (k2 > k3) ? k2 : k3;          // computes w -> no readlane on the path
      ull km = (ka > kb) ? ka : kb;
      w = (int)~(unsigned)(km & 0xffffffffULL);
      if (t == 0) {
        whist[it] = w;                       // ds_write: cheap lgkm drain at the barrier
        __hip_atomic_store(widx + (size_t)b * MC + it, (unsigned)w,
                           __ATOMIC_RELAXED, __HIP_MEMORY_SCOPE_AGENT);  // fire-and-forget
      }
    }
    __syncthreads();
    for (int s = t; s < MC; s += 256) {      // one-shot output writeback
      int wi = whist[s];
      float4 wp = pts[wi];
      size_t o = (size_t)b * MC + s;
      cent_out[3*o] = wp.x; cent_out[3*o+1] = wp.y; cent_out[3*o+2] = wp.z;
      batch_out[o] = (float)b;  // batch = arange // NP == cloud index
    }
    return;
  }

  // ======================= Worker path: blocks 16..255 =======================
  const int wv = t >> 6, lane = t & 63;
  const int quad = lane >> 4, col16 = lane & 15;
  ushort_t* w1L = (ushort_t*)smem;             // 12288 B
  ushort_t* w2L = (ushort_t*)(smem + 12288);   // 8192 B
  ushort_t* w3L = (ushort_t*)(smem + 20480);   // 16384 B
  for (int e = t; e < 4 * 3 * 64; e += 256) wfrag_entry(W1, w1L, e, 3, CIN + 3, HID);
  for (int e = t; e < 4 * 2 * 64; e += 256) wfrag_entry(W2, w2L, e, 2, HID, HID);
  for (int e = t; e < 8 * 2 * 64; e += 256) wfrag_entry(W3, w3L, e, 2, HID, OUTD);
  __syncthreads();   // only block-wide sync in worker path (all 4 waves present)

  char* base = smem + 36864 + wv * 9472;       // per-wave slice
  float* ld = (float*)base;                    // [512] f32 (neigh phase)
  int* li = (int*)(base + 2048);               // [512] i32 (neigh phase)
  ushort_t* hb = (ushort_t*)base;              // 64x72 bf16 = 9216 B (mlp phase, aliases ld/li)
  int* nsel = (int*)(base + 9216);             // [64] selected neighbor indices
  const float R2 = (float)(0.2 * 0.2);
  const int gwave = (blk - NB) * 4 + wv;       // 0..959

  for (int r = gwave; r < NB * MC; r += 960) {
    const int s = r >> 4, b = r & 15;          // availability order: s outer, b inner
    const int c = b * MC + s;
    const size_t bbase = (size_t)b * NP;
    // ---- wait for this center's index (steady state: already published) ----
    unsigned wpub = 0;
    if (lane == 0) {
      wpub = __hip_atomic_load(widx + c, __ATOMIC_RELAXED, __HIP_MEMORY_SCOPE_AGENT);
      while (wpub == WSENT) {
        __builtin_amdgcn_s_sleep(32);
        wpub = __hip_atomic_load(widx + c, __ATOMIC_RELAXED, __HIP_MEMORY_SCOPE_AGENT);
      }
    }
    const int wc = __shfl((int)wpub, 0);
    const float cx = point[(bbase + wc) * 3];
    const float cy = point[(bbase + wc) * 3 + 1];
    const float cz = point[(bbase + wc) * 3 + 2];

    // ---- neigh: compact in-ball candidates (wave-local, exact r0 logic) ----
    const float* p = point + bbase * 3;
    int cnt = 0;
    for (int sb = 0; sb < NP / 64; ++sb) {
      int j = sb * 64 + lane;
      float d2 = dist2e(cx, cy, cz, p[3*j], p[3*j+1], p[3*j+2]);
      bool v = d2 < R2;
      ull m = __ballot(v);
      if (v) {
        int pos = cnt + __popcll(m & ((1ull << lane) - 1ull));
        if (pos < 512) { ld[pos] = d2; li[pos] = j; }
      }
      cnt += __popcll(m);
    }
    if (cnt > 512) cnt = 512;
    asm volatile("s_waitcnt lgkmcnt(0)" ::: "memory");
    if (cnt <= KNN) {
      nsel[lane] = (lane < cnt) ? li[lane] : 0;
    } else {
      unsigned ob[8]; int oi[8];
#pragma unroll
      for (int rr = 0; rr < 8; ++rr) {
        int s2 = lane + rr * 64;
        if (s2 < cnt) { ob[rr] = __float_as_uint(ld[s2]); oi[rr] = li[s2]; }
        else { ob[rr] = 0xFFFFFFFFu; oi[rr] = 0; }
      }
      unsigned L = 0u, H = 0x3D23D70Au;     // tau = 64th-smallest d2 bit pattern
      while (L < H) {
        unsigned mid = (L + H) >> 1;
        int cle = 0;
#pragma unroll
        for (int rr = 0; rr < 8; ++rr) cle += (int)__popcll(__ballot(ob[rr] <= mid));
        if (cle >= KNN) H = mid; else L = mid + 1;
      }
      const unsigned tau = H;
      int c_lt = 0;
#pragma unroll
      for (int rr = 0; rr < 8; ++rr) c_lt += (int)__popcll(__ballot(ob[rr] < tau));
      const int need = KNN - c_lt;
      const ull below = (1ull << lane) - 1ull;
      int outpos = 0, eqc = 0;
#pragma unroll
      for (int rr = 0; rr < 8; ++rr) {       // slot order == index order => top_k stability
        ull meq = __ballot(ob[rr] == tau);
        int eqrank = eqc + (int)__popcll(meq & below);
        bool sel = (ob[rr] < tau) || ((ob[rr] == tau) && (eqrank < need));
        ull msel = __ballot(sel);
        if (sel) {
          int posn = outpos + (int)__popcll(msel & below);
          nsel[posn] = oi[rr];
        }
        outpos += (int)__popcll(msel);
        eqc += (int)__popcll(meq);
      }
    }
    const int nv = (cnt < KNN) ? cnt : KNN;
    asm volatile("s_waitcnt lgkmcnt(0)" ::: "memory");
    const int jg = nsel[lane];

    // ---- MLP (identical math to r0 mlp_kernel; xyz gathered f32 + RNE-converted) ----
    const float* pp = point + (bbase + jg) * 3;
    const float dxx = pp[0] - cx, dyy = pp[1] - cy, dzz = pp[2] - cz;

    bf16x8 a1[4][2];
    bf16x8 a2[4];
#pragma unroll
    for (int mt = 0; mt < 4; ++mt) {
      int srcl = mt * 16 + col16;
      int jmt = __shfl(jg, srcl);
      const float* xr = xyz + (bbase + (size_t)jmt) * CIN + quad * 8;
      float4 f0 = *(const float4*)(xr);
      float4 f1 = *(const float4*)(xr + 4);
      float4 f2 = *(const float4*)(xr + 32);
      float4 f3 = *(const float4*)(xr + 36);
      bf16x8 v0, v1;
      v0[0] = (short)f2bf(f0.x); v0[1] = (short)f2bf(f0.y);
      v0[2] = (short)f2bf(f0.z); v0[3] = (short)f2bf(f0.w);
      v0[4] = (short)f2bf(f1.x); v0[5] = (short)f2bf(f1.y);
      v0[6] = (short)f2bf(f1.z); v0[7] = (short)f2bf(f1.w);
      v1[0] = (short)f2bf(f2.x); v1[1] = (short)f2bf(f2.y);
      v1[2] = (short)f2bf(f2.z); v1[3] = (short)f2bf(f2.w);
      v1[4] = (short)f2bf(f3.x); v1[5] = (short)f2bf(f3.y);
      v1[6] = (short)f2bf(f3.z); v1[7] = (short)f2bf(f3.w);
      a1[mt][0] = v0;
      a1[mt][1] = v1;
      float ddx = __shfl(dxx, srcl), ddy = __shfl(dyy, srcl), ddz = __shfl(dzz, srcl);
      bf16x8 t2 = {0, 0, 0, 0, 0, 0, 0, 0};
      if (quad == 0) {
        t2[0] = (short)f2bf(ddx); t2[1] = (short)f2bf(ddy); t2[2] = (short)f2bf(ddz);
      }
      a2[mt] = t2;
    }

    bf16x8 bw1[4][3];
#pragma unroll
    for (int nt = 0; nt < 4; ++nt)
#pragma unroll
      for (int ks = 0; ks < 3; ++ks)
        bw1[nt][ks] = *(const bf16x8*)(w1L + ((size_t)(nt * 3 + ks) * 64 + lane) * 8);
    f32x4 acc1[4][4];
#pragma unroll
    for (int nt = 0; nt < 4; ++nt) {
      float bv = b1[nt * 16 + col16];
#pragma unroll
      for (int mt = 0; mt < 4; ++mt) { f32x4 v = {bv, bv, bv, bv}; acc1[mt][nt] = v; }
    }
#pragma unroll
    for (int mt = 0; mt < 4; ++mt)
#pragma unroll
      for (int nt = 0; nt < 4; ++nt) {
        acc1[mt][nt] = __builtin_amdgcn_mfma_f32_16x16x32_bf16(a1[mt][0], bw1[nt][0], acc1[mt][nt], 0, 0, 0);
        acc1[mt][nt] = __builtin_amdgcn_mfma_f32_16x16x32_bf16(a1[mt][1], bw1[nt][1], acc1[mt][nt], 0, 0, 0);
        acc1[mt][nt] = __builtin_amdgcn_mfma_f32_16x16x32_bf16(a2[mt],    bw1[nt][2], acc1[mt][nt], 0, 0, 0);
      }
#pragma unroll
    for (int mt = 0; mt < 4; ++mt)
#pragma unroll
      for (int nt = 0; nt < 4; ++nt)
#pragma unroll
        for (int reg = 0; reg < 4; ++reg) {
          int row = quad * 4 + reg + mt * 16;
          hb[row * 72 + col16 + nt * 16] = f2bf(fmaxf(acc1[mt][nt][reg], 0.f));
        }

    bf16x8 a21[4][2];
#pragma unroll
    for (int mt = 0; mt < 4; ++mt)
#pragma unroll
      for (int ks = 0; ks < 2; ++ks)
        a21[mt][ks] = *(const bf16x8*)(hb + (col16 + mt * 16) * 72 + ks * 32 + quad * 8);
    bf16x8 bw2[4][2];
#pragma unroll
    for (int nt = 0; nt < 4; ++nt)
#pragma unroll
      for (int ks = 0; ks < 2; ++ks)
        bw2[nt][ks] = *(const bf16x8*)(w2L + ((size_t)(nt * 2 + ks) * 64 + lane) * 8);
    f32x4 acc2[4][4];
#pragma unroll
    for (int nt = 0; nt < 4; ++nt) {
      float bv = b2[nt * 16 + col16];
#pragma unroll
      for (int mt = 0; mt < 4; ++mt) { f32x4 v = {bv, bv, bv, bv}; acc2[mt][nt] = v; }
    }
#pragma unroll
    for (int mt = 0; mt < 4; ++mt)
#pragma unroll
      for (int nt = 0; nt < 4; ++nt) {
        acc2[mt][nt] = __builtin_amdgcn_mfma_f32_16x16x32_bf16(a21[mt][0], bw2[nt][0], acc2[mt][nt], 0, 0, 0);
        acc2[mt][nt] = __builtin_amdgcn_mfma_f32_16x16x32_bf16(a21[mt][1], bw2[nt][1], acc2[mt][nt], 0, 0, 0);
      }
#pragma unroll
    for (int mt = 0; mt < 4; ++mt)
#pragma unroll
      for (int nt = 0; nt < 4; ++nt)
#pragma unroll
        for (int reg = 0; reg < 4; ++reg) {
          int row = quad * 4 + reg + mt * 16;
          hb[row * 72 + col16 + nt * 16] = f2bf(fmaxf(acc2[mt][nt][reg], 0.f));
        }

    bf16x8 a3[4][2];
#pragma unroll
    for (int mt = 0; mt < 4; ++mt)
#pragma unroll
      for (int ks = 0; ks < 2; ++ks)
        a3[mt][ks] = *(const bf16x8*)(hb + (col16 + mt * 16) * 72 + ks * 32 + quad * 8);
#pragma unroll
    for (int pass = 0; pass < 2; ++pass) {
      bf16x8 bw3[4][2];
#pragma unroll
      for (int nt = 0; nt < 4; ++nt)
#pragma unroll
        for (int ks = 0; ks < 2; ++ks)
          bw3[nt][ks] = *(const bf16x8*)(w3L + ((size_t)((pass * 4 + nt) * 2 + ks) * 64 + lane) * 8);
      f32x4 acc3[4][4];
#pragma unroll
      for (int nt = 0; nt < 4; ++nt) {
        float bv = b3[pass * 64 + nt * 16 + col16];
#pragma unroll
        for (int mt = 0; mt < 4; ++mt) { f32x4 v = {bv, bv, bv, bv}; acc3[mt][nt] = v; }
      }
#pragma unroll
      for (int mt = 0; mt < 4; ++mt)
#pragma unroll
        for (int nt = 0; nt < 4; ++nt) {
          acc3[mt][nt] = __builtin_amdgcn_mfma_f32_16x16x32_bf16(a3[mt][0], bw3[nt][0], acc3[mt][nt], 0, 0, 0);
          acc3[mt][nt] = __builtin_amdgcn_mfma_f32_16x16x32_bf16(a3[mt][1], bw3[nt][1], acc3[mt][nt], 0, 0, 0);
        }
#pragma unroll
      for (int nt = 0; nt < 4; ++nt) {
        float m = -1.0e30f;
#pragma unroll
        for (int mt = 0; mt < 4; ++mt)
#pragma unroll
          for (int reg = 0; reg < 4; ++reg) {
            int row = quad * 4 + reg + mt * 16;
            float v = fmaxf(acc3[mt][nt][reg], 0.f);
            m = fmaxf(m, (row < nv) ? v : -1.0e30f);
          }
        m = fmaxf(m, __shfl_xor(m, 16));
        m = fmaxf(m, __shfl_xor(m, 32));
        if (quad == 0)
          out[(size_t)c * OUTD + pass * 64 + nt * 16 + col16] = m;
      }
    }
  }
}

extern "C" void kernel_launch(void* const* d_in, const int* in_sizes, int n_in,
                              void* d_out, int out_size, void* d_ws, size_t ws_size,
                              hipStream_t stream) {
  const float* xyz   = (const float*)d_in[0];
  const float* point = (const float*)d_in[1];
  // d_in[2] = batch (values == cloud index by construction), d_in[3] = num_samples (64)
  const float* W1 = (const float*)d_in[4];
  const float* b1 = (const float*)d_in[5];
  const float* W2 = (const float*)d_in[6];
  const float* b2 = (const float*)d_in[7];
  const float* W3 = (const float*)d_in[8];
  const float* b3 = (const float*)d_in[9];

  float* out       = (float*)d_out;                     // [16384,128]
  float* cent_out  = out + (size_t)NB * MC * OUTD;      // [16384,3]
  float* batch_out = cent_out + (size_t)NB * MC * 3;    // [16384] (f32 values)

  unsigned* widx = (unsigned*)d_ws;                     // 65536 B: per-center FPS index

  init_widx<<<64, 256, 0, stream>>>(widx);
  mega_kernel<<<256, 256, 0, stream>>>(point, xyz, W1, W2, W3, b1, b2, b3,
                                       widx, out, cent_out, batch_out);
}

// Round 5
// 751.080 us; speedup vs baseline: 1.0107x; 1.0107x over previous
//
#include <hip/hip_runtime.h>
#include <cstdint>

#define NB 16      // clouds
#define NP 4096    // points per cloud
#define MC 1024    // FPS centers per cloud
#define KNN 64     // neighbors
#define CIN 64     // input feature dim
#define HID 64
#define OUTD 128

typedef __attribute__((ext_vector_type(8))) short bf16x8;
typedef __attribute__((ext_vector_type(4))) float f32x4;
typedef __attribute__((ext_vector_type(2))) float f32x2;
typedef unsigned long long ull;
typedef unsigned short ushort_t;

#define F32_INF __int_as_float(0x7f800000)
#define WSENT 0xFFFFFFFFu

// LDS-only barrier: orders DS ops across the block WITHOUT draining vmcnt
// (keeps t0's fire-and-forget widx publish store in flight).
#define BAR_LGKM() asm volatile("s_waitcnt lgkmcnt(0)\n\ts_barrier" ::: "memory")

// Bit-exact (vs numpy f32) squared distance: no FMA contraction, numpy sum order.
__device__ __forceinline__ float dist2e(float ax, float ay, float az,
                                        float bx, float by, float bz) {
  float dx = __fsub_rn(ax, bx);
  float dy = __fsub_rn(ay, by);
  float dz = __fsub_rn(az, bz);
  return __fadd_rn(__fadd_rn(__fmul_rn(dx, dx), __fmul_rn(dy, dy)), __fmul_rn(dz, dz));
}

// f32 -> bf16 with round-to-nearest-even.
__device__ __forceinline__ ushort_t f2bf(float f) {
  unsigned u = __float_as_uint(f);
  unsigned r = (u + 0x7FFFu + ((u >> 16) & 1u)) >> 16;
  return (ushort_t)r;
}

// ---- DPP helpers: 64-bit key max-reduce on the VALU pipe ----
template <int CTRL>
__device__ __forceinline__ ull kshift(ull k) {
  int lo = (int)(unsigned)(k & 0xffffffffULL);
  int hi = (int)(unsigned)(k >> 32);
  lo = __builtin_amdgcn_update_dpp(lo, lo, CTRL, 0xf, 0xf, false);
  hi = __builtin_amdgcn_update_dpp(hi, hi, CTRL, 0xf, 0xf, false);
  return ((ull)(unsigned)hi << 32) | (ull)(unsigned)lo;
}
template <int CTRL>
__device__ __forceinline__ ull kred(ull k) {
  ull o = kshift<CTRL>(k);
  return (o > k) ? o : k;
}

// ---------- W -> MFMA B-fragment layout ----------
__device__ __forceinline__ void wfrag_entry(const float* __restrict__ W,
                                            ushort_t* __restrict__ out,
                                            int e, int KS, int K, int N) {
  int lane = e & 63, t2 = e >> 6;
  int ks = t2 % KS, nt = t2 / KS;
  int n = nt * 16 + (lane & 15);
  int kb = ks * 32 + ((lane >> 4) & 3) * 8;
#pragma unroll
  for (int j = 0; j < 8; ++j) {
    int k = kb + j;
    float v = (k < K) ? W[(size_t)k * N + n] : 0.f;
    out[(size_t)e * 8 + j] = f2bf(v);
  }
}

// Re-poison the per-center published-index array each launch (ws persists).
__global__ void init_widx(unsigned* __restrict__ widx) {
  int i = blockIdx.x * 256 + threadIdx.x;
  if (i < NB * MC) widx[i] = WSENT;
}

// ================= Mega-kernel: FPS producers (blocks 0..15) + streaming workers =================
// FPS core = round-0 proven structure (4 waves, u64-key DPP reduce, one lgkm barrier/iter).
// r3 falsified the vmcnt-drain theory. Remaining gap candidates: (T1) 2-blocks/CU
// co-residency stealing issue slots from issue-bound FPS blocks; (T2) worker per-center
// tail time. r5 (r4 with LDS trimmed to <=128KiB proven territory): cloud-per-block
// workers (16 clouds x 15 blocks); each block stages its cloud's points into LDS ONCE
// as SoA px/py/pz (48KB) -> neigh scan + geometry read LDS; block LDS = 123904B
// => 2 blocks/CU impossible (2x123904 > 160KiB) => 1 block/CU for ALL blocks (kills T1).
__global__ __launch_bounds__(256) void mega_kernel(
    const float* __restrict__ point, const float* __restrict__ xyz,
    const float* __restrict__ W1, const float* __restrict__ W2, const float* __restrict__ W3,
    const float* __restrict__ b1, const float* __restrict__ b2, const float* __restrict__ b3,
    unsigned* __restrict__ widx,
    float* __restrict__ out, float* __restrict__ cent_out, float* __restrict__ batch_out) {
#pragma clang fp contract(off)
  __shared__ char __attribute__((aligned(16))) smem[123904];
  const int blk = blockIdx.x;
  const int t = threadIdx.x;

  if (blk < NB) {
    // ======================= FPS path (round-0 core) =======================
    const int b = blk;
    const int lane = t & 63, wid = t >> 6;
    float4* pts = (float4*)smem;                 // 65536 B
    ull* kbuf = (ull*)(smem + 65536);            // 2*4 slots = 64 B
    int* whist = (int*)(smem + 65600);           // 4096 B
    const float* p = point + (size_t)b * NP * 3;
    for (int i = t; i < NP; i += 256) {
      float4 v; v.x = p[3 * i]; v.y = p[3 * i + 1]; v.z = p[3 * i + 2]; v.w = 0.f;
      pts[i] = v;
    }
    if (t == 0) {
      whist[0] = 0;  // sample 0 is index 0
      __hip_atomic_store(widx + (size_t)b * MC, 0u, __ATOMIC_RELAXED, __HIP_MEMORY_SCOPE_AGENT);
    }
    __syncthreads();
    f32x2 qx2[8], qy2[8], qz2[8], d2v[8];
#pragma unroll
    for (int k = 0; k < 8; ++k) {
      float4 v0 = pts[t * 16 + 2 * k];
      float4 v1 = pts[t * 16 + 2 * k + 1];
      qx2[k].x = v0.x; qx2[k].y = v1.x;
      qy2[k].x = v0.y; qy2[k].y = v1.y;
      qz2[k].x = v0.z; qz2[k].y = v1.z;
      d2v[k].x = F32_INF; d2v[k].y = F32_INF;   // min(inf, d0) == d0 exactly
    }
    int w = 0;
    for (int it = 1; it < MC; ++it) {
      float4 wp = pts[w];
      f32x2 wxx; wxx.x = wp.x; wxx.y = wp.x;
      f32x2 wyy; wyy.x = wp.y; wyy.y = wp.y;
      f32x2 wzz; wzz.x = wp.z; wzz.y = wp.z;
      float bd = -1.0f; int br = 0;
#pragma unroll
      for (int k = 0; k < 8; ++k) {   // packed dist + min-update + first-max argmax
        f32x2 dx = qx2[k] - wxx;
        f32x2 dy = qy2[k] - wyy;
        f32x2 dz = qz2[k] - wzz;
        f32x2 nd = (dx * dx + dy * dy) + dz * dz;  // per-element numpy order, no fma
        f32x2 dv;
        dv.x = fminf(d2v[k].x, nd.x);
        dv.y = fminf(d2v[k].y, nd.y);
        d2v[k] = dv;
        bool p1 = dv.y > dv.x;                     // strict: tie keeps lower r
        float pd = p1 ? dv.y : dv.x;
        int pr = 2 * k + (p1 ? 1 : 0);
        if (pd > bd) { bd = pd; br = pr; }         // strict: first-occurrence wins
      }
      unsigned gi = (unsigned)(t * 16 + br);
      ull key = ((ull)__float_as_uint(bd) << 32) | (ull)(unsigned)~gi;
      key = kred<0x111>(key);  // row_shr:1
      key = kred<0x112>(key);  // row_shr:2
      key = kred<0x114>(key);  // row_shr:4
      key = kred<0x118>(key);  // row_shr:8   -> lane 15/31/47/63 = row max
      key = kred<0x142>(key);  // row_bcast:15
      key = kred<0x143>(key);  // row_bcast:31 -> lane 63 = wave max
      const int par = it & 1;                // parity: slot reused only after 2 barriers
      if (lane == 63) kbuf[par * 4 + wid] = key;
      BAR_LGKM();                            // LDS-only barrier: publish store stays in flight
      ull k0 = kbuf[par * 4 + 0], k1 = kbuf[par * 4 + 1];
      ull k2 = kbuf[par * 4 + 2], k3 = kbuf[par * 4 + 3];
      ull ka = (k0 > k1) ? k0 : k1;          // uniform LDS broadcast reads; every lane
      ull kb = (k2 > k3) ? k2 : k3;          // computes w -> no readlane on the path
      ull km = (ka > kb) ? ka : kb;
      w = (int)~(unsigned)(km & 0xffffffffULL);
      if (t == 0) {
        whist[it] = w;                       // ds_write: cheap lgkm drain at the barrier
        __hip_atomic_store(widx + (size_t)b * MC + it, (unsigned)w,
                           __ATOMIC_RELAXED, __HIP_MEMORY_SCOPE_AGENT);  // fire-and-forget
      }
    }
    __syncthreads();
    for (int s = t; s < MC; s += 256) {      // one-shot output writeback
      int wi = whist[s];
      float4 wp = pts[wi];
      size_t o = (size_t)b * MC + s;
      cent_out[3*o] = wp.x; cent_out[3*o+1] = wp.y; cent_out[3*o+2] = wp.z;
      batch_out[o] = (float)b;  // batch = arange // NP == cloud index
    }
    return;
  }

  // ======================= Worker path: blocks 16..255, cloud-per-block =======================
  const int wv = t >> 6, lane = t & 63;
  const int quad = lane >> 4, col16 = lane & 15;
  const int wb = blk - NB;                     // 0..239
  const int b = wb / 15;                       // cloud (15 blocks per cloud)
  const int jcl = wb % 15;                     // block index within cloud
  const int q = jcl * 4 + wv;                  // wave's residue class 0..59
  const size_t bbase = (size_t)b * NP;

  ushort_t* w1L = (ushort_t*)smem;             // 12288 B
  ushort_t* w2L = (ushort_t*)(smem + 12288);   // 8192 B
  ushort_t* w3L = (ushort_t*)(smem + 20480);   // 16384 B
  float* px = (float*)(smem + 36864);          // 16384 B
  float* py = (float*)(smem + 53248);          // 16384 B
  float* pz = (float*)(smem + 69632);          // 16384 B
  for (int e = t; e < 4 * 3 * 64; e += 256) wfrag_entry(W1, w1L, e, 3, CIN + 3, HID);
  for (int e = t; e < 4 * 2 * 64; e += 256) wfrag_entry(W2, w2L, e, 2, HID, HID);
  for (int e = t; e < 8 * 2 * 64; e += 256) wfrag_entry(W3, w3L, e, 2, HID, OUTD);
  {
    const float* pcl = point + bbase * 3;
    for (int i = t; i < NP; i += 256) {
      px[i] = pcl[3*i]; py[i] = pcl[3*i+1]; pz[i] = pcl[3*i+2];
    }
  }
  __syncthreads();   // only block-wide sync in worker path (all 4 waves present)

  char* base = smem + 86016 + wv * 9472;       // per-wave slice
  float* ld = (float*)base;                    // [512] f32 (neigh phase)
  int* li = (int*)(base + 2048);               // [512] i32 (neigh phase)
  ushort_t* hb = (ushort_t*)base;              // 64x72 bf16 = 9216 B (mlp phase, aliases ld/li)
  int* nsel = (int*)(base + 9216);             // [64] selected neighbor indices
  const float R2 = (float)(0.2 * 0.2);

  for (int s = q; s < MC; s += 60) {           // arrival order within this cloud
    const int c = b * MC + s;
    // ---- wait for this center's index (steady state: already published) ----
    unsigned wpub = 0;
    if (lane == 0) {
      wpub = __hip_atomic_load(widx + c, __ATOMIC_RELAXED, __HIP_MEMORY_SCOPE_AGENT);
      while (wpub == WSENT) {
        __builtin_amdgcn_s_sleep(32);
        wpub = __hip_atomic_load(widx + c, __ATOMIC_RELAXED, __HIP_MEMORY_SCOPE_AGENT);
      }
    }
    const int wc = __shfl((int)wpub, 0);
    const float cx = px[wc], cy = py[wc], cz = pz[wc];

    // ---- neigh: compact in-ball candidates from LDS (wave-local, exact logic) ----
    int cnt = 0;
    for (int sb = 0; sb < NP / 64; ++sb) {
      int j = sb * 64 + lane;
      float d2 = dist2e(cx, cy, cz, px[j], py[j], pz[j]);
      bool v = d2 < R2;
      ull m = __ballot(v);
      if (v) {
        int pos = cnt + __popcll(m & ((1ull << lane) - 1ull));
        if (pos < 512) { ld[pos] = d2; li[pos] = j; }
      }
      cnt += __popcll(m);
    }
    if (cnt > 512) cnt = 512;
    asm volatile("s_waitcnt lgkmcnt(0)" ::: "memory");
    if (cnt <= KNN) {
      nsel[lane] = (lane < cnt) ? li[lane] : 0;
    } else {
      unsigned ob[8]; int oi[8];
#pragma unroll
      for (int rr = 0; rr < 8; ++rr) {
        int s2 = lane + rr * 64;
        if (s2 < cnt) { ob[rr] = __float_as_uint(ld[s2]); oi[rr] = li[s2]; }
        else { ob[rr] = 0xFFFFFFFFu; oi[rr] = 0; }
      }
      unsigned L = 0u, H = 0x3D23D70Au;     // tau = 64th-smallest d2 bit pattern
      while (L < H) {
        unsigned mid = (L + H) >> 1;
        int cle = 0;
#pragma unroll
        for (int rr = 0; rr < 8; ++rr) cle += (int)__popcll(__ballot(ob[rr] <= mid));
        if (cle >= KNN) H = mid; else L = mid + 1;
      }
      const unsigned tau = H;
      int c_lt = 0;
#pragma unroll
      for (int rr = 0; rr < 8; ++rr) c_lt += (int)__popcll(__ballot(ob[rr] < tau));
      const int need = KNN - c_lt;
      const ull below = (1ull << lane) - 1ull;
      int outpos = 0, eqc = 0;
#pragma unroll
      for (int rr = 0; rr < 8; ++rr) {       // slot order == index order => top_k stability
        ull meq = __ballot(ob[rr] == tau);
        int eqrank = eqc + (int)__popcll(meq & below);
        bool sel = (ob[rr] < tau) || ((ob[rr] == tau) && (eqrank < need));
        ull msel = __ballot(sel);
        if (sel) {
          int posn = outpos + (int)__popcll(msel & below);
          nsel[posn] = oi[rr];
        }
        outpos += (int)__popcll(msel);
        eqc += (int)__popcll(meq);
      }
    }
    const int nv = (cnt < KNN) ? cnt : KNN;
    asm volatile("s_waitcnt lgkmcnt(0)" ::: "memory");
    const int jg = nsel[lane];

    // ---- MLP (identical math; geometry from LDS, xyz gathered f32 + RNE-converted) ----
    const float dxx = px[jg] - cx, dyy = py[jg] - cy, dzz = pz[jg] - cz;

    bf16x8 a1[4][2];
    bf16x8 a2[4];
#pragma unroll
    for (int mt = 0; mt < 4; ++mt) {
      int srcl = mt * 16 + col16;
      int jmt = __shfl(jg, srcl);
      const float* xr = xyz + (bbase + (size_t)jmt) * CIN + quad * 8;
      float4 f0 = *(const float4*)(xr);
      float4 f1 = *(const float4*)(xr + 4);
      float4 f2 = *(const float4*)(xr + 32);
      float4 f3 = *(const float4*)(xr + 36);
      bf16x8 v0, v1;
      v0[0] = (short)f2bf(f0.x); v0[1] = (short)f2bf(f0.y);
      v0[2] = (short)f2bf(f0.z); v0[3] = (short)f2bf(f0.w);
      v0[4] = (short)f2bf(f1.x); v0[5] = (short)f2bf(f1.y);
      v0[6] = (short)f2bf(f1.z); v0[7] = (short)f2bf(f1.w);
      v1[0] = (short)f2bf(f2.x); v1[1] = (short)f2bf(f2.y);
      v1[2] = (short)f2bf(f2.z); v1[3] = (short)f2bf(f2.w);
      v1[4] = (short)f2bf(f3.x); v1[5] = (short)f2bf(f3.y);
      v1[6] = (short)f2bf(f3.z); v1[7] = (short)f2bf(f3.w);
      a1[mt][0] = v0;
      a1[mt][1] = v1;
      float ddx = __shfl(dxx, srcl), ddy = __shfl(dyy, srcl), ddz = __shfl(dzz, srcl);
      bf16x8 t2 = {0, 0, 0, 0, 0, 0, 0, 0};
      if (quad == 0) {
        t2[0] = (short)f2bf(ddx); t2[1] = (short)f2bf(ddy); t2[2] = (short)f2bf(ddz);
      }
      a2[mt] = t2;
    }

    bf16x8 bw1[4][3];
#pragma unroll
    for (int nt = 0; nt < 4; ++nt)
#pragma unroll
      for (int ks = 0; ks < 3; ++ks)
        bw1[nt][ks] = *(const bf16x8*)(w1L + ((size_t)(nt * 3 + ks) * 64 + lane) * 8);
    f32x4 acc1[4][4];
#pragma unroll
    for (int nt = 0; nt < 4; ++nt) {
      float bv = b1[nt * 16 + col16];
#pragma unroll
      for (int mt = 0; mt < 4; ++mt) { f32x4 v = {bv, bv, bv, bv}; acc1[mt][nt] = v; }
    }
#pragma unroll
    for (int mt = 0; mt < 4; ++mt)
#pragma unroll
      for (int nt = 0; nt < 4; ++nt) {
        acc1[mt][nt] = __builtin_amdgcn_mfma_f32_16x16x32_bf16(a1[mt][0], bw1[nt][0], acc1[mt][nt], 0, 0, 0);
        acc1[mt][nt] = __builtin_amdgcn_mfma_f32_16x16x32_bf16(a1[mt][1], bw1[nt][1], acc1[mt][nt], 0, 0, 0);
        acc1[mt][nt] = __builtin_amdgcn_mfma_f32_16x16x32_bf16(a2[mt],    bw1[nt][2], acc1[mt][nt], 0, 0, 0);
      }
#pragma unroll
    for (int mt = 0; mt < 4; ++mt)
#pragma unroll
      for (int nt = 0; nt < 4; ++nt)
#pragma unroll
        for (int reg = 0; reg < 4; ++reg) {
          int row = quad * 4 + reg + mt * 16;
          hb[row * 72 + col16 + nt * 16] = f2bf(fmaxf(acc1[mt][nt][reg], 0.f));
        }

    bf16x8 a21[4][2];
#pragma unroll
    for (int mt = 0; mt < 4; ++mt)
#pragma unroll
      for (int ks = 0; ks < 2; ++ks)
        a21[mt][ks] = *(const bf16x8*)(hb + (col16 + mt * 16) * 72 + ks * 32 + quad * 8);
    bf16x8 bw2[4][2];
#pragma unroll
    for (int nt = 0; nt < 4; ++nt)
#pragma unroll
      for (int ks = 0; ks < 2; ++ks)
        bw2[nt][ks] = *(const bf16x8*)(w2L + ((size_t)(nt * 2 + ks) * 64 + lane) * 8);
    f32x4 acc2[4][4];
#pragma unroll
    for (int nt = 0; nt < 4; ++nt) {
      float bv = b2[nt * 16 + col16];
#pragma unroll
      for (int mt = 0; mt < 4; ++mt) { f32x4 v = {bv, bv, bv, bv}; acc2[mt][nt] = v; }
    }
#pragma unroll
    for (int mt = 0; mt < 4; ++mt)
#pragma unroll
      for (int nt = 0; nt < 4; ++nt) {
        acc2[mt][nt] = __builtin_amdgcn_mfma_f32_16x16x32_bf16(a21[mt][0], bw2[nt][0], acc2[mt][nt], 0, 0, 0);
        acc2[mt][nt] = __builtin_amdgcn_mfma_f32_16x16x32_bf16(a21[mt][1], bw2[nt][1], acc2[mt][nt], 0, 0, 0);
      }
#pragma unroll
    for (int mt = 0; mt < 4; ++mt)
#pragma unroll
      for (int nt = 0; nt < 4; ++nt)
#pragma unroll
        for (int reg = 0; reg < 4; ++reg) {
          int row = quad * 4 + reg + mt * 16;
          hb[row * 72 + col16 + nt * 16] = f2bf(fmaxf(acc2[mt][nt][reg], 0.f));
        }

    bf16x8 a3[4][2];
#pragma unroll
    for (int mt = 0; mt < 4; ++mt)
#pragma unroll
      for (int ks = 0; ks < 2; ++ks)
        a3[mt][ks] = *(const bf16x8*)(hb + (col16 + mt * 16) * 72 + ks * 32 + quad * 8);
#pragma unroll
    for (int pass = 0; pass < 2; ++pass) {
      bf16x8 bw3[4][2];
#pragma unroll
      for (int nt = 0; nt < 4; ++nt)
#pragma unroll
        for (int ks = 0; ks < 2; ++ks)
          bw3[nt][ks] = *(const bf16x8*)(w3L + ((size_t)((pass * 4 + nt) * 2 + ks) * 64 + lane) * 8);
      f32x4 acc3[4][4];
#pragma unroll
      for (int nt = 0; nt < 4; ++nt) {
        float bv = b3[pass * 64 + nt * 16 + col16];
#pragma unroll
        for (int mt = 0; mt < 4; ++mt) { f32x4 v = {bv, bv, bv, bv}; acc3[mt][nt] = v; }
      }
#pragma unroll
      for (int mt = 0; mt < 4; ++mt)
#pragma unroll
        for (int nt = 0; nt < 4; ++nt) {
          acc3[mt][nt] = __builtin_amdgcn_mfma_f32_16x16x32_bf16(a3[mt][0], bw3[nt][0], acc3[mt][nt], 0, 0, 0);
          acc3[mt][nt] = __builtin_amdgcn_mfma_f32_16x16x32_bf16(a3[mt][1], bw3[nt][1], acc3[mt][nt], 0, 0, 0);
        }
#pragma unroll
      for (int nt = 0; nt < 4; ++nt) {
        float m = -1.0e30f;
#pragma unroll
        for (int mt = 0; mt < 4; ++mt)
#pragma unroll
          for (int reg = 0; reg < 4; ++reg) {
            int row = quad * 4 + reg + mt * 16;
            float v = fmaxf(acc3[mt][nt][reg], 0.f);
            m = fmaxf(m, (row < nv) ? v : -1.0e30f);
          }
        m = fmaxf(m, __shfl_xor(m, 16));
        m = fmaxf(m, __shfl_xor(m, 32));
        if (quad == 0)
          out[(size_t)c * OUTD + pass * 64 + nt * 16 + col16] = m;
      }
    }
  }
}

extern "C" void kernel_launch(void* const* d_in, const int* in_sizes, int n_in,
                              void* d_out, int out_size, void* d_ws, size_t ws_size,
                              hipStream_t stream) {
  const float* xyz   = (const float*)d_in[0];
  const float* point = (const float*)d_in[1];
  // d_in[2] = batch (values == cloud index by construction), d_in[3] = num_samples (64)
  const float* W1 = (const float*)d_in[4];
  const float* b1 = (const float*)d_in[5];
  const float* W2 = (const float*)d_in[6];
  const float* b2 = (const float*)d_in[7];
  const float* W3 = (const float*)d_in[8];
  const float* b3 = (const float*)d_in[9];

  float* out       = (float*)d_out;                     // [16384,128]
  float* cent_out  = out + (size_t)NB * MC * OUTD;      // [16384,3]
  float* batch_out = cent_out + (size_t)NB * MC * 3;    // [16384] (f32 values)

  unsigned* widx = (unsigned*)d_ws;                     // 65536 B: per-center FPS index

  init_widx<<<64, 256, 0, stream>>>(widx);
  mega_kernel<<<256, 256, 0, stream>>>(point, xyz, W1, W2, W3, b1, b2, b3,
                                       widx, out, cent_out, batch_out);
}